// Round 8
// baseline (430.305 us; speedup 1.0000x reference)
//
#include <hip/hip_runtime.h>
#include <math.h>

#define BB 256
#define KK 2
#define EE 16
#define DD 512
#define BK (BB*KK)   // 512
#define NP 4         // K-dim partials (i-split)

// ws layout (ints/floats over same buffer):
//   int  wlist[EE*BK]   @ int 1024
//   int  blist[EE*BK]   @ int 10240
//   int  wchunks        @ int 18432  ([0]=count, [1..] = e | r0<<8 | rows<<20)
//   int  bchunks        @ int 18560
//   f32  16 partial slabs @ f32 20480: slab(z,p) = (z*NP+p)*SLAB, each BK*DD
//        z: 0=iv 1=ov 2=dv 3=bv; p: i-range [p*128,(p+1)*128)
#define WCH 18432
#define BCH 18560
#define WS_F_BASE 20480
#define SLAB (BK*DD)

// ---------------------------------------------------------------- kernel A
__global__ void build_lists(const int* __restrict__ widx,
                            const int* __restrict__ bidx,
                            int* __restrict__ ws) {
    __shared__ int scw[16], scb[16];
    int* wlist = ws + 1024;
    int* blist = ws + 10240;
    const int t = threadIdx.x;        // 0..511
    if (t < 16) { scw[t] = 0; scb[t] = 0; }
    __syncthreads();
    int e = widx[t];
    int p = atomicAdd(&scw[e], 1);
    wlist[e * BK + p] = t;
    int eb = bidx[t];
    int pb = atomicAdd(&scb[eb], 1);
    blist[eb * BK + pb] = t;
    __syncthreads();
    if (t == 0) {
        int nc = 0;
        for (int e2 = 0; e2 < 16; ++e2) {
            int n = scw[e2];
            for (int r = 0; r < n; r += 32)
                ws[WCH + 1 + nc++] = e2 | (r << 8) | (min(32, n - r) << 20);
        }
        ws[WCH] = nc;
    }
    if (t == 64) {
        int nc = 0;
        for (int e2 = 0; e2 < 16; ++e2) {
            int n = scb[e2];
            for (int r = 0; r < n; r += 32)
                ws[BCH + 1 + nc++] = e2 | (r << 8) | (min(32, n - r) << 20);
        }
        ws[BCH] = nc;
    }
}

// ---------------------------------------------------------------- kernel B (v4)
// grid (2 colhalves, 32 chunk slots, 16 z*p), block 256.
// Chunk = expert e, up to 32 (b,k) rows; i in [ip*128,+128), cols [bx*256,+256).
// 32-row chunks: mean ~1.3 chunks/expert -> W slab streamed ~1.3x (was 2.2x).
// W staged through LDS in 32x256 subtiles via float4 loads; per inner i:
// 1 LDS W read + 8 broadcast b128 + 32 FMA.
__launch_bounds__(256)
__global__ void expert_vm(const float* __restrict__ x,
                          const float* __restrict__ w_in,
                          const float* __restrict__ w_out,
                          const float* __restrict__ w_diag,
                          const float* __restrict__ w_bias,
                          const int* __restrict__ ws_i,
                          float* __restrict__ ws_f) {
    const int zp = blockIdx.z;                 // 0..15
    const int z = zp >> 2, ip = zp & 3;
    const int* ch = ws_i + ((z < 3) ? WCH : BCH);
    const int slot = blockIdx.y;
    if (slot >= ch[0]) return;
    const int desc = ch[1 + slot];
    const int e = desc & 0xff, r0 = (desc >> 8) & 0xfff, rows = desc >> 20;
    const int* list = ws_i + ((z < 3) ? 1024 : 10240) + e * BK + r0;
    const int i0 = ip * 128;
    const int colbase = blockIdx.x * 256;
    const float* W = (z == 0 ? w_in : z == 1 ? w_out : z == 2 ? w_diag : w_bias)
                     + (size_t)e * DD * DD + (size_t)i0 * DD + colbase;
    float* out = ws_f + WS_F_BASE + (size_t)zp * SLAB;

    __shared__ int plist[32];
    __shared__ float4 xs[128][8];      // [i_local][q]: rows 4q..4q+3 (16KB)
    __shared__ float  Wt[32][256];     // W subtile (32KB)
    const int t = threadIdx.x;
    if (t < 32) plist[t] = (t < rows) ? list[t] : -1;
    __syncthreads();
    #pragma unroll
    for (int k = 0; k < 4; ++k) {
        int idx = t + k * 256;         // 0..1023
        int i = idx >> 3, q = idx & 7;
        int p0 = plist[q * 4 + 0], p1 = plist[q * 4 + 1];
        int p2 = plist[q * 4 + 2], p3 = plist[q * 4 + 3];
        float4 v;
        // plist entries are (b,k) flat 0..511; x row is p>>1.
        v.x = (p0 >= 0) ? x[(p0 >> 1) * DD + i0 + i] : 0.f;
        v.y = (p1 >= 0) ? x[(p1 >> 1) * DD + i0 + i] : 0.f;
        v.z = (p2 >= 0) ? x[(p2 >> 1) * DD + i0 + i] : 0.f;
        v.w = (p3 >= 0) ? x[(p3 >> 1) * DD + i0 + i] : 0.f;
        xs[i][q] = v;
    }

    float acc[32];
    #pragma unroll
    for (int r = 0; r < 32; ++r) acc[r] = 0.f;

    // Wt stage indices: 32 rows x 64 float4-cols = 2048 float4 / 256 thr = 8 ea
    const int srow = t >> 6, sc4 = (t & 63);   // j adds 4 rows each step

    for (int s = 0; s < 4; ++s) {              // 4 i-subtiles of 32
        __syncthreads();                       // protect Wt from prev readers
        #pragma unroll
        for (int j = 0; j < 8; ++j) {
            int row = srow + j * 4;            // 0..31
            float4 v = *(const float4*)(W + (size_t)(s * 32 + row) * DD + sc4 * 4);
            *(float4*)&Wt[row][sc4 * 4] = v;
        }
        __syncthreads();
        #pragma unroll 4
        for (int ii = 0; ii < 32; ++ii) {
            int i = s * 32 + ii;
            float w = Wt[ii][t];               // stride-1, conflict-free
            #pragma unroll
            for (int q = 0; q < 8; ++q) {
                float4 xv = xs[i][q];          // broadcast b128 reads
                acc[q * 4 + 0] += xv.x * w;
                acc[q * 4 + 1] += xv.y * w;
                acc[q * 4 + 2] += xv.z * w;
                acc[q * 4 + 3] += xv.w * w;
            }
        }
    }
    const int col = colbase + t;
    #pragma unroll
    for (int r = 0; r < 32; ++r) {
        int p = plist[r];
        if (p >= 0) out[(size_t)p * DD + col] = acc[r];
    }
}

// ---------------------------------------------------------------- kernel C
// grid (8 chunks, 256 batch), block 256. Closed-form LayerNorm of the
// rank-2+diag mixture, folded into per-row coefficients:
//   out[i][j] = af1*ov1[j] + af2*ov2[j] + cm  (+ cc at j==i)
// chunk-0 blocks also emit the bias mix.
__launch_bounds__(256)
__global__ void gen_write(const float* __restrict__ ws_f,
                          const float* __restrict__ wp,
                          const float* __restrict__ bp,
                          float* __restrict__ outp,
                          float* __restrict__ outb) {
    const int b = blockIdx.y;
    const int chunk = blockIdx.x;          // 64-row chunk
    const float* base = ws_f + WS_F_BASE;

    __shared__ float4 ov1v[128], ov2v[128];
    __shared__ float S[5], red[20];
    __shared__ float saf1[64], saf2[64], scm[64], scc[64];
    const int t = threadIdx.x;
    const float* ov1 = (const float*)ov1v;
    const float* ov2 = (const float*)ov2v;

    {   // stage ov rows (sum of NP partial slabs, z=1 -> slabs 4..7)
        const int tt = t & 127;
        const int row = b * 2 + (t >> 7);
        float sx = 0.f, sy = 0.f, sz = 0.f, sw = 0.f;
        #pragma unroll
        for (int pp = 0; pp < NP; ++pp) {
            const float4* q4 = (const float4*)(base + (size_t)(4 + pp) * SLAB
                                               + (size_t)row * DD);
            float4 v = q4[tt];
            sx += v.x; sy += v.y; sz += v.z; sw += v.w;
        }
        float4 s = make_float4(sx, sy, sz, sw);
        if (t < 128) ov1v[tt] = s; else ov2v[tt] = s;
    }
    __syncthreads();

    float v0a = ov1[t], v0b = ov1[t + 256], v1a = ov2[t], v1b = ov2[t + 256];
    float s[5];
    s[0] = v0a + v0b;
    s[1] = v1a + v1b;
    s[2] = v0a * v0a + v0b * v0b;
    s[3] = v0a * v1a + v0b * v1b;
    s[4] = v1a * v1a + v1b * v1b;
    #pragma unroll
    for (int off = 32; off; off >>= 1) {
        #pragma unroll
        for (int q = 0; q < 5; ++q) s[q] += __shfl_down(s[q], off);
    }
    const int lane = t & 63, wv = t >> 6;
    if (lane == 0) {
        #pragma unroll
        for (int q = 0; q < 5; ++q) red[wv * 5 + q] = s[q];
    }
    __syncthreads();
    if (t == 0) {
        #pragma unroll
        for (int q = 0; q < 5; ++q) S[q] = red[q] + red[5 + q] + red[10 + q] + red[15 + q];
    }
    __syncthreads();

    if (t < 64) {
        const float S1 = S[0], S2 = S[1], S11 = S[2], S12 = S[3], S22 = S[4];
        int i = chunk * 64 + t;
        float wp0 = wp[b * 2], wp1 = wp[b * 2 + 1];
        float iv1 = 0.f, iv2 = 0.f, dv1 = 0.f, dv2 = 0.f;
        #pragma unroll
        for (int pp = 0; pp < NP; ++pp) {
            const float* s0 = base + (size_t)(0 + pp) * SLAB;   // iv slabs 0..3
            const float* s2 = base + (size_t)(8 + pp) * SLAB;   // dv slabs 8..11
            iv1 += s0[(size_t)(b * 2 + 0) * DD + i];
            iv2 += s0[(size_t)(b * 2 + 1) * DD + i];
            dv1 += s2[(size_t)(b * 2 + 0) * DD + i];
            dv2 += s2[(size_t)(b * 2 + 1) * DD + i];
        }
        float a1 = wp0 * iv1;
        float a2 = wp1 * iv2;
        float dd = wp0 * dv1 + wp1 * dv2;
        float mu = (a1 * S1 + a2 * S2 + dd) * (1.0f / DD);
        float e2 = (a1 * a1 * S11 + 2.0f * a1 * a2 * S12 + a2 * a2 * S22
                    + 2.0f * (a1 * ov1[i] + a2 * ov2[i]) * dd + dd * dd) * (1.0f / DD);
        float var = e2 - mu * mu;
        float rs = rsqrtf(var + 1e-5f);
        saf1[t] = a1 * rs;
        saf2[t] = a2 * rs;
        scm[t]  = -mu * rs;
        scc[t]  = dd * rs;
    }
    __syncthreads();

    const int ci = t & 127, rh = t >> 7;
    const float4 o1 = ov1v[ci], o2 = ov2v[ci];   // loop-invariant, hoisted
    const int jj = ci * 4;
    float* obase = outp + ((size_t)b * DD + chunk * 64) * DD;
    #pragma unroll 2
    for (int rr = 0; rr < 32; ++rr) {
        int r = rr * 2 + rh;
        int irow = chunk * 64 + r;
        float af1 = saf1[r], af2 = saf2[r], cm = scm[r], cc = scc[r];
        float4 w;
        w.x = fmaf(af1, o1.x, fmaf(af2, o2.x, cm));
        w.y = fmaf(af1, o1.y, fmaf(af2, o2.y, cm));
        w.z = fmaf(af1, o1.z, fmaf(af2, o2.z, cm));
        w.w = fmaf(af1, o1.w, fmaf(af2, o2.w, cm));
        int d = irow - jj;
        w.x += (d == 0) ? cc : 0.f;
        w.y += (d == 1) ? cc : 0.f;
        w.z += (d == 2) ? cc : 0.f;
        w.w += (d == 3) ? cc : 0.f;
        ((float4*)(obase + (size_t)r * DD))[ci] = w;
    }

    // fused bias mix: chunk-0 blocks write outb[b][:]
    if (chunk == 0) {
        float p0 = bp[b * 2], p1 = bp[b * 2 + 1];
        float s0a = 0.f, s0b = 0.f, s1a = 0.f, s1b = 0.f;
        #pragma unroll
        for (int pp = 0; pp < NP; ++pp) {
            const float* bv = base + (size_t)(12 + pp) * SLAB;   // bv slabs 12..15
            s0a += bv[(size_t)(b * 2 + 0) * DD + t];
            s0b += bv[(size_t)(b * 2 + 0) * DD + t + 256];
            s1a += bv[(size_t)(b * 2 + 1) * DD + t];
            s1b += bv[(size_t)(b * 2 + 1) * DD + t + 256];
        }
        outb[(size_t)b * DD + t]       = p0 * s0a + p1 * s1a;
        outb[(size_t)b * DD + t + 256] = p0 * s0b + p1 * s1b;
    }
}

// ---------------------------------------------------------------- launch
extern "C" void kernel_launch(void* const* d_in, const int* in_sizes, int n_in,
                              void* d_out, int out_size, void* d_ws, size_t ws_size,
                              hipStream_t stream) {
    const float* x      = (const float*)d_in[0];
    const float* wprobs = (const float*)d_in[1];
    const float* bprobs = (const float*)d_in[2];
    const float* w_in   = (const float*)d_in[3];
    const float* w_out  = (const float*)d_in[4];
    const float* w_diag = (const float*)d_in[5];
    const float* w_bias = (const float*)d_in[6];
    const int*   widx   = (const int*)d_in[7];
    const int*   bidx   = (const int*)d_in[8];
    float* out = (float*)d_out;
    int*   wsI = (int*)d_ws;
    float* wsF = (float*)d_ws;

    build_lists<<<1, BK, 0, stream>>>(widx, bidx, wsI);

    expert_vm<<<dim3(2, 32, 16), 256, 0, stream>>>(x, w_in, w_out, w_diag, w_bias,
                                                   wsI, wsF);

    gen_write<<<dim3(8, BB), 256, 0, stream>>>(wsF, wprobs, bprobs, out,
                                               out + (size_t)BB * DD * DD);
}